// Round 3
// baseline (1153.389 us; speedup 1.0000x reference)
//
#include <hip/hip_runtime.h>
#include <hip/hip_bf16.h>
#include <cstdint>

using bf16 = __hip_bfloat16;
typedef __attribute__((ext_vector_type(8))) short short8;
typedef __attribute__((ext_vector_type(4))) float floatx4;

#define NTOK 32768
#define IND 1024
#define HIDD 512
#define OUTD 1024
#define NEXP 6
#define N1 3072

#define GLDS16(g, l) __builtin_amdgcn_global_load_lds( \
    (const __attribute__((address_space(1))) void*)(g), \
    (__attribute__((address_space(3))) void*)(l), 16, 0, 0)

// ---------- weight transpose+cast: W1T[n][k] = w1[e,k,j], n=e*512+j ----------
__global__ __launch_bounds__(256) void cast_w1_kernel(const float* __restrict__ w1,
                                                      bf16* __restrict__ w1t) {
    int idx = blockIdx.x * 256 + threadIdx.x;      // idx = n*1024 + k
    int k = idx & 1023;
    int n = idx >> 10;
    int e = n >> 9, j = n & 511;
    w1t[idx] = __float2bfloat16(w1[(size_t)e * (IND * HIDD) + (size_t)k * HIDD + j]);
}

// ---------- W2T[o][n] = w2[e,j,o], n=e*512+j ----------
__global__ __launch_bounds__(256) void cast_w2_kernel(const float* __restrict__ w2,
                                                      bf16* __restrict__ w2t) {
    int n = blockIdx.x * 256 + threadIdx.x;        // 0..3071
    int o = blockIdx.y;
    int e = n >> 9, j = n & 511;
    w2t[(size_t)o * N1 + n] = __float2bfloat16(w2[(size_t)e * (HIDD * OUTD) + (size_t)j * OUTD + o]);
}

// ---------- gate weights + x cast to bf16 (one wave per row) ----------
__global__ __launch_bounds__(256) void gate_castx_kernel(
    const float* __restrict__ x,
    const float* __restrict__ g2w, const float* __restrict__ g2b,
    const float* __restrict__ g3w, const float* __restrict__ g3b,
    bf16* __restrict__ xb, float* __restrict__ gw, int chunk_base)
{
    int w = threadIdx.x >> 6, l = threadIdx.x & 63;
    int lrow = blockIdx.x * 4 + w;                 // chunk-local row
    size_t grow = (size_t)chunk_base + lrow;       // global row
    const float* xr = x + grow * IND + l * 16;
    float a2 = 0.f, a30 = 0.f, a31 = 0.f, a32 = 0.f;
    __align__(16) bf16 xo[16];
    #pragma unroll
    for (int i = 0; i < 16; i += 4) {
        float4 v = *(const float4*)(xr + i);
        const float* vp = (const float*)&v;
        #pragma unroll
        for (int j = 0; j < 4; ++j) {
            float xv = vp[j];
            int gi = l * 16 + i + j;
            a2  += xv * g2w[gi];
            a30 += xv * g3w[gi * 3 + 0];
            a31 += xv * g3w[gi * 3 + 1];
            a32 += xv * g3w[gi * 3 + 2];
            xo[i + j] = __float2bfloat16(xv);
        }
    }
    short8* dst = (short8*)(xb + (size_t)lrow * IND + l * 16);
    dst[0] = ((short8*)xo)[0];
    dst[1] = ((short8*)xo)[1];
    #pragma unroll
    for (int s = 32; s > 0; s >>= 1) {
        a2  += __shfl_down(a2, s);
        a30 += __shfl_down(a30, s);
        a31 += __shfl_down(a31, s);
        a32 += __shfl_down(a32, s);
    }
    if (l == 0) {
        float alpha = 1.f / (1.f + __expf(-(a2 + g2b[0])));
        float z0 = a30 + g3b[0], z1 = a31 + g3b[1], z2 = a32 + g3b[2];
        float mx = fmaxf(z0, fmaxf(z1, z2));
        float e0 = __expf(z0 - mx), e1 = __expf(z1 - mx), e2 = __expf(z2 - mx);
        float inv = 1.f / (e0 + e1 + e2);
        float s0 = e0 * inv, s1 = e1 * inv, s2 = e2 * inv;
        float* o = gw + grow * NEXP;
        o[0] = (1.f - alpha) * s0; o[1] = (1.f - alpha) * s1; o[2] = (1.f - alpha) * s2;
        o[3] = alpha * s0;         o[4] = alpha * s1;         o[5] = alpha * s2;
    }
}

// ---------- m97-style 128x128 bf16 GEMM, A[M][K], Bm = B^T [N][K] ----------
// EPI==1: Cb[row][col(N1)] = bf16( relu(acc + bias[col]) * gw[row, col>>9] )
// EPI==2: Cf[row][col(OUTD)] = acc + sum_e gw[row,e]*bias[e*OUTD+col]
template<int KD, int EPI>
__global__ __launch_bounds__(256) void gemm_kernel(
    const bf16* __restrict__ A, const bf16* __restrict__ Bm,
    bf16* __restrict__ Cb, float* __restrict__ Cf,
    const float* __restrict__ bias, const float* __restrict__ gw,
    int chunk_base, int grid_n)
{
    __shared__ __align__(16) bf16 lA[128 * 32];
    __shared__ __align__(16) bf16 lB[128 * 32];
    int nwg = gridDim.x;
    int bid = blockIdx.x;
    int wg = (bid & 7) * (nwg >> 3) + (bid >> 3);  // XCD-contiguous (nwg % 8 == 0 always)
    int bm = wg / grid_n, bn = wg % grid_n;
    int t = threadIdx.x;
    int srow = t >> 2;                             // staging row 0..63
    int sk = (t & 3) * 8;                          // staging k elem offset
    const bf16* ga = A + (size_t)(bm * 128 + srow) * KD + sk;
    const bf16* gb = Bm + (size_t)(bn * 128 + srow) * KD + sk;
    bf16* la = lA + t * 8;                         // linear LDS dest (16 B per thread)
    bf16* lb = lB + t * 8;

    floatx4 acc[4][4];
    #pragma unroll
    for (int i = 0; i < 4; ++i)
        #pragma unroll
        for (int j = 0; j < 4; ++j) {
            floatx4 z = {0.f, 0.f, 0.f, 0.f};
            acc[i][j] = z;
        }

    int w = t >> 6, l = t & 63;
    int wr = (w >> 1) * 64, wc = (w & 1) * 64;     // wave tile 64x64
    int fr = l & 15, fq = l >> 4;

    for (int kt = 0; kt < KD / 32; ++kt) {
        GLDS16(ga + kt * 32, la);
        GLDS16(ga + kt * 32 + (size_t)64 * KD, la + 64 * 32);
        GLDS16(gb + kt * 32, lb);
        GLDS16(gb + kt * 32 + (size_t)64 * KD, lb + 64 * 32);
        __syncthreads();
        short8 af[4], bfr[4];
        #pragma unroll
        for (int m = 0; m < 4; ++m)
            af[m] = *(const short8*)(lA + (wr + m * 16 + fr) * 32 + fq * 8);
        #pragma unroll
        for (int n = 0; n < 4; ++n)
            bfr[n] = *(const short8*)(lB + (wc + n * 16 + fr) * 32 + fq * 8);
        #pragma unroll
        for (int m = 0; m < 4; ++m)
            #pragma unroll
            for (int n = 0; n < 4; ++n)
                acc[m][n] = __builtin_amdgcn_mfma_f32_16x16x32_bf16(af[m], bfr[n], acc[m][n], 0, 0, 0);
        __syncthreads();
    }

    if (EPI == 1) {
        int e = (bn * 128) >> 9;                   // 128-col tile lies in one expert
        #pragma unroll
        for (int m = 0; m < 4; ++m) {
            #pragma unroll
            for (int rg = 0; rg < 4; ++rg) {
                int row = bm * 128 + wr + m * 16 + fq * 4 + rg;
                float g = gw[((size_t)chunk_base + row) * NEXP + e];
                #pragma unroll
                for (int n = 0; n < 4; ++n) {
                    int col = bn * 128 + wc + n * 16 + fr;
                    float v = acc[m][n][rg] + bias[col];
                    v = v > 0.f ? v : 0.f;
                    Cb[(size_t)row * N1 + col] = __float2bfloat16(v * g);
                }
            }
        }
    } else {
        #pragma unroll
        for (int m = 0; m < 4; ++m) {
            #pragma unroll
            for (int rg = 0; rg < 4; ++rg) {
                int row = bm * 128 + wr + m * 16 + fq * 4 + rg;
                const float* gr = gw + ((size_t)chunk_base + row) * NEXP;
                float g0 = gr[0], g1 = gr[1], g2 = gr[2], g3 = gr[3], g4 = gr[4], g5 = gr[5];
                #pragma unroll
                for (int n = 0; n < 4; ++n) {
                    int col = bn * 128 + wc + n * 16 + fr;
                    float bb = g0 * bias[col] + g1 * bias[OUTD + col] + g2 * bias[2 * OUTD + col]
                             + g3 * bias[3 * OUTD + col] + g4 * bias[4 * OUTD + col] + g5 * bias[5 * OUTD + col];
                    Cf[((size_t)chunk_base + row) * OUTD + col] = acc[m][n][rg] + bb;
                }
            }
        }
    }
}

// ---------- ws-free correctness fallback (slow, only if ws tiny) ----------
__global__ __launch_bounds__(256) void naive_kernel(
    const float* __restrict__ x,
    const float* __restrict__ g2w, const float* __restrict__ g2b,
    const float* __restrict__ g3w, const float* __restrict__ g3b,
    const float* __restrict__ w1, const float* __restrict__ b1,
    const float* __restrict__ w2, const float* __restrict__ b2,
    float* __restrict__ out)
{
    __shared__ float xr[IND];
    __shared__ float h[HIDD];
    __shared__ float oacc[OUTD];
    __shared__ float red[4][4];
    __shared__ float gws[NEXP];
    int row = blockIdx.x, t = threadIdx.x;
    for (int i = t; i < IND; i += 256) xr[i] = x[(size_t)row * IND + i];
    for (int i = t; i < OUTD; i += 256) oacc[i] = 0.f;
    __syncthreads();
    float a2 = 0, a30 = 0, a31 = 0, a32 = 0;
    for (int i = t; i < IND; i += 256) {
        float xv = xr[i];
        a2 += xv * g2w[i]; a30 += xv * g3w[i * 3]; a31 += xv * g3w[i * 3 + 1]; a32 += xv * g3w[i * 3 + 2];
    }
    #pragma unroll
    for (int s = 32; s > 0; s >>= 1) {
        a2 += __shfl_down(a2, s); a30 += __shfl_down(a30, s);
        a31 += __shfl_down(a31, s); a32 += __shfl_down(a32, s);
    }
    int w = t >> 6, l = t & 63;
    if (l == 0) { red[w][0] = a2; red[w][1] = a30; red[w][2] = a31; red[w][3] = a32; }
    __syncthreads();
    if (t == 0) {
        float A2 = red[0][0] + red[1][0] + red[2][0] + red[3][0];
        float z0 = red[0][1] + red[1][1] + red[2][1] + red[3][1] + g3b[0];
        float z1 = red[0][2] + red[1][2] + red[2][2] + red[3][2] + g3b[1];
        float z2 = red[0][3] + red[1][3] + red[2][3] + red[3][3] + g3b[2];
        float alpha = 1.f / (1.f + __expf(-(A2 + g2b[0])));
        float mx = fmaxf(z0, fmaxf(z1, z2));
        float e0 = __expf(z0 - mx), e1 = __expf(z1 - mx), e2 = __expf(z2 - mx);
        float inv = 1.f / (e0 + e1 + e2);
        gws[0] = (1.f - alpha) * e0 * inv; gws[1] = (1.f - alpha) * e1 * inv; gws[2] = (1.f - alpha) * e2 * inv;
        gws[3] = alpha * e0 * inv;         gws[4] = alpha * e1 * inv;         gws[5] = alpha * e2 * inv;
    }
    __syncthreads();
    for (int e = 0; e < NEXP; ++e) {
        const float* W1 = w1 + (size_t)e * IND * HIDD;
        for (int j = t; j < HIDD; j += 256) {
            float s = 0.f;
            for (int i = 0; i < IND; ++i) s += xr[i] * W1[(size_t)i * HIDD + j];
            s += b1[e * HIDD + j];
            h[j] = s > 0.f ? s : 0.f;
        }
        __syncthreads();
        const float* W2 = w2 + (size_t)e * HIDD * OUTD;
        float g = gws[e];
        for (int o = t; o < OUTD; o += 256) {
            float s = 0.f;
            for (int j = 0; j < HIDD; ++j) s += h[j] * W2[(size_t)j * OUTD + o];
            oacc[o] += g * (s + b2[e * OUTD + o]);
        }
        __syncthreads();
    }
    for (int i = t; i < OUTD; i += 256) out[(size_t)row * OUTD + i] = oacc[i];
}

extern "C" void kernel_launch(void* const* d_in, const int* in_sizes, int n_in,
                              void* d_out, int out_size, void* d_ws, size_t ws_size,
                              hipStream_t stream) {
    const float* x   = (const float*)d_in[0];
    const float* g2w = (const float*)d_in[1];
    const float* g2b = (const float*)d_in[2];
    const float* g3w = (const float*)d_in[3];
    const float* g3b = (const float*)d_in[4];
    const float* w1  = (const float*)d_in[5];
    const float* b1  = (const float*)d_in[6];
    const float* w2  = (const float*)d_in[7];
    const float* b2  = (const float*)d_in[8];
    float* out = (float*)d_out;

    size_t off = 0;
    auto take = [&](size_t bytes) -> char* {
        char* p = (char*)d_ws + off;
        off += (bytes + 255) & ~(size_t)255;
        return p;
    };
    bf16* w1t = (bf16*)take((size_t)N1 * IND * 2);
    bf16* w2t = (bf16*)take((size_t)OUTD * N1 * 2);
    float* gw = (float*)take((size_t)NTOK * NEXP * 4);
    size_t fixed = off;

    int CB = NTOK;  // chunk of batch rows processed per pipeline pass
    while (CB >= 128 && fixed + (size_t)CB * (IND * 2 + N1 * 2) > ws_size) CB >>= 1;
    if (CB < 128) {
        naive_kernel<<<NTOK, 256, 0, stream>>>(x, g2w, g2b, g3w, g3b, w1, b1, w2, b2, out);
        return;
    }
    bf16* xb = (bf16*)take((size_t)CB * IND * 2);
    bf16* hb = (bf16*)take((size_t)CB * N1 * 2);

    cast_w1_kernel<<<(N1 * IND) / 256, 256, 0, stream>>>(w1, w1t);
    cast_w2_kernel<<<dim3(N1 / 256, OUTD), 256, 0, stream>>>(w2, w2t);
    for (int cb = 0; cb < NTOK; cb += CB) {
        gate_castx_kernel<<<CB / 4, 256, 0, stream>>>(x, g2w, g2b, g3w, g3b, xb, gw, cb);
        gemm_kernel<IND, 1><<<(CB / 128) * (N1 / 128), 256, 0, stream>>>(xb, w1t, hb, nullptr, b1, gw, cb, N1 / 128);
        gemm_kernel<N1, 2><<<(CB / 128) * (OUTD / 128), 256, 0, stream>>>(hb, w2t, nullptr, out, b2, gw, cb, OUTD / 128);
    }
}